// Round 9
// baseline (110.710 us; speedup 1.0000x reference)
//
#include <hip/hip_runtime.h>
#include <hip/hip_bf16.h>

#define FRADIUS 1.3f
#define FSTEP (2.0f * 1.3f / 128.0f)

typedef __attribute__((ext_vector_type(8))) short short8;
typedef __attribute__((ext_vector_type(16))) float f32x16;

#define MFMA32(a, b, c) __builtin_amdgcn_mfma_f32_32x32x16_bf16((a), (b), (c), 0, 0, 0)

// pack two f32 -> bf16x2 in a dword (RNE); low 16 bits = a
__device__ __forceinline__ unsigned pk2(float a, float b) {
    __hip_bfloat162 hh = __float22bfloat162_rn(make_float2(a, b));
    union { __hip_bfloat162 h; unsigned u; } cv;
    cv.h = hh;
    return cv.u;
}

__device__ __forceinline__ void ray_aabb(float ox, float oy, float oz,
                                         float dx, float dy, float dz,
                                         float& tnear, float& tmax) {
    float sdx = (fabsf(dx) < 1e-9f) ? 1e-9f : dx;
    float sdy = (fabsf(dy) < 1e-9f) ? 1e-9f : dy;
    float sdz = (fabsf(dz) < 1e-9f) ? 1e-9f : dz;
    float t1x = (-FRADIUS - ox) / sdx, t2x = (FRADIUS - ox) / sdx;
    float t1y = (-FRADIUS - oy) / sdy, t2y = (FRADIUS - oy) / sdy;
    float t1z = (-FRADIUS - oz) / sdz, t2z = (FRADIUS - oz) / sdz;
    float tmin = fmaxf(fmaxf(fminf(t1x, t2x), fminf(t1y, t2y)), fminf(t1z, t2z));
    tmax = fminf(fminf(fmaxf(t1x, t2x), fmaxf(t1y, t2y)), fmaxf(t1z, t2z));
    tnear = fmaxf(tmin, 0.0f);
}

// ---------------- weight prep: 32x32x16 A-frags (lane l: A[m=l&31][k=(l>>5)*8+j]) ----------------
// fid map: s0(32->128): 0..7 = nt*2+kt | s1(128->128): 8..39 = 8+nt*8+kt | s2(128->16pad32): 40..47 = 40+kt
//          c0(32->64): 48..51 = 48+nt*2+kt | c1(64->64): 52..59 = 52+nt*4+kt | c2(64->3pad32): 60..63 = 60+kt
__global__ void prep_weights_kernel(const float* __restrict__ s_w0, const float* __restrict__ s_w1,
                                    const float* __restrict__ s_w2, const float* __restrict__ c_w0,
                                    const float* __restrict__ c_w1, const float* __restrict__ c_w2,
                                    uint4* __restrict__ ws) {
    int fid = blockIdx.x;   // 64 frags
    int l = threadIdx.x;    // 64 lanes
    int h = l >> 5, m = l & 31;
    int layer, nt = 0, kt = 0;
    if (fid < 8)       { layer = 0; nt = fid >> 1; kt = fid & 1; }
    else if (fid < 40) { layer = 1; int f = fid - 8;  nt = f >> 3; kt = f & 7; }
    else if (fid < 48) { layer = 2; kt = fid - 40; }
    else if (fid < 52) { layer = 3; int f = fid - 48; nt = f >> 1; kt = f & 1; }
    else if (fid < 60) { layer = 4; int f = fid - 52; nt = f >> 2; kt = f & 3; }
    else               { layer = 5; kt = fid - 60; }
    int n = nt * 32 + m;
    float v[8];
#pragma unroll
    for (int j = 0; j < 8; ++j) {
        int k = kt * 16 + h * 8 + j;
        float x;
        if (layer == 0)      x = s_w0[k * 128 + n];
        else if (layer == 1) x = s_w1[k * 128 + n];
        else if (layer == 2) x = (n < 16) ? s_w2[k * 16 + n] : 0.0f;
        else if (layer == 3) x = (k < 16) ? c_w0[k * 64 + n]
                                 : ((k == 16) ? 0.0f : c_w0[(k - 1) * 64 + n]);  // zero row: sigma unused
        else if (layer == 4) x = c_w1[k * 64 + n];
        else                 x = (n < 3) ? c_w2[k * 3 + n] : 0.0f;
        v[j] = x;
    }
    uint4 u;
    u.x = pk2(v[0], v[1]); u.y = pk2(v[2], v[3]);
    u.z = pk2(v[4], v[5]); u.w = pk2(v[6], v[7]);
    ws[fid * 64 + l] = u;
}

// Build next-layer B-frag from packed activations PK (per-lane dword array, static idx only).
// Derivation (validated r5-r8): target dword u of lane (h,c): pd = BASE + 2h + (u&1), source half = u>>1.
#define BUILD_B(B, PK, BASE) do {                                         \
    unsigned own0 = h ? (PK)[(BASE) + 2] : (PK)[(BASE) + 0];              \
    unsigned own1 = h ? (PK)[(BASE) + 3] : (PK)[(BASE) + 1];              \
    unsigned snd0 = h ? (PK)[(BASE) + 0] : (PK)[(BASE) + 2];              \
    unsigned snd1 = h ? (PK)[(BASE) + 1] : (PK)[(BASE) + 3];              \
    unsigned r0 = (unsigned)__shfl_xor((int)snd0, 32, 64);                \
    unsigned r1 = (unsigned)__shfl_xor((int)snd1, 32, 64);                \
    union { unsigned u[4]; short8 v; } bb;                                \
    bb.u[0] = h ? r0 : own0;  bb.u[1] = h ? r1 : own1;                    \
    bb.u[2] = h ? own0 : r0;  bb.u[3] = h ? own1 : r1;                    \
    (B) = bb.v; } while (0)

// ---------------- fused kernel: gather + 32x32x16 MLP + composite ----------------
// block = 512 thd = 8 waves = 2 rays. Phase 1: thd 0..255 gather the block's 256 samples
// into LDS (B-frag layout) while thd 256..511 stage weight frags fid 0..51 into LDS.
// Phase 2 (per wave = 32 samples): MLP chain identical to r8's mlp_kernel6, with c1/c2
// weights read from global (L2-hot). Phase 3: waves 0,1 composite the 2 rays.
// LDS = 52 KB weights + 16 KB fv + 4 KB comp = 72 KB -> 2 blocks/CU; VGPR cap 128 (4 waves/EU).
__global__ __launch_bounds__(512, 4) void fused_kernel(
    const float* __restrict__ rays_o, const float* __restrict__ rays_d,
    const float* __restrict__ G1, const float* __restrict__ Fg,
    const uint4* __restrict__ wsg, float* __restrict__ out) {

    __shared__ uint4 wlds[52 * 64];     // 52 KiB: frags 0..51
    __shared__ uint4 fvb[8 * 4 * 32];   // 16 KiB: [group g][kt*2+h][c]
    __shared__ float4 comp[2][128];

    const int tid = threadIdx.x;
    const int w = tid >> 6;           // 0..7
    const int lane = tid & 63;
    const int h = lane >> 5;
    const int c = lane & 31;
    const int wr = w >> 2;            // local ray 0/1
    const int chunk = w & 3;          // 32-sample chunk within ray
    const int ray = blockIdx.x * 2 + wr;
    const int cbase = chunk * 32;

    // ================= phase 1: gather (thd<256) / weight staging (thd>=256) ==============
    if (tid < 256) {
        const int idx = blockIdx.x * 256 + tid;      // global sample index
        const int gray = idx >> 7;
        const int s = idx & 127;

        const float ox = rays_o[gray * 3 + 0], oy = rays_o[gray * 3 + 1], oz = rays_o[gray * 3 + 2];
        const float dx = rays_d[gray * 3 + 0], dy = rays_d[gray * 3 + 1], dz = rays_d[gray * 3 + 2];

        float tnear, tmax;
        ray_aabb(ox, oy, oz, dx, dy, dz, tnear, tmax);
        float t = tnear + (float)s * FSTEP;
        bool maskb = (t < tmax) && (tmax > tnear);

        uint4* op = &fvb[(tid >> 5) * 128 + (tid & 31)];
        if (!maskb) {
            uint4 z = {0u, 0u, 0u, 0u};
#pragma unroll
            for (int q = 0; q < 4; ++q) op[q * 32] = z;
        } else {
            float px = ox + dx * t, py = oy + dy * t, pz = oz + dz * t;
            const float invR = 1.0f / FRADIUS;
            float cx = px * invR, cy = py * invR, cz = pz * invR;

            // G1 trilinear (256^3 x 3)
            float fx = fminf(fmaxf((cx + 1.0f) * 0.5f * 255.0f, 0.0f), 255.0f);
            float fy = fminf(fmaxf((cy + 1.0f) * 0.5f * 255.0f, 0.0f), 255.0f);
            float fz = fminf(fmaxf((cz + 1.0f) * 0.5f * 255.0f, 0.0f), 255.0f);
            float x0f = floorf(fx), y0f = floorf(fy), z0f = floorf(fz);
            float wx = fx - x0f, wy = fy - y0f, wz = fz - z0f;
            int x0 = (int)x0f, y0 = (int)y0f, z0 = (int)z0f;
            int x1 = min(x0 + 1, 255), y1 = min(y0 + 1, 255), z1 = min(z0 + 1, 255);
            float g1x = 0.f, g1y = 0.f, g1z = 0.f;
            {
                float wz0 = 1.f - wz, wy0 = 1.f - wy, wx0 = 1.f - wx;
#pragma unroll
                for (int cc = 0; cc < 8; ++cc) {
                    int zz = (cc & 4) ? z1 : z0;
                    int yy = (cc & 2) ? y1 : y0;
                    int xx = (cc & 1) ? x1 : x0;
                    float wgt = ((cc & 4) ? wz : wz0) * ((cc & 2) ? wy : wy0) * ((cc & 1) ? wx : wx0);
                    int gidx = (((zz << 8) | yy) << 8 | xx) * 3;
                    g1x = fmaf(wgt, G1[gidx + 0], g1x);
                    g1y = fmaf(wgt, G1[gidx + 1], g1y);
                    g1z = fmaf(wgt, G1[gidx + 2], g1z);
                }
            }

            // Fg trilinear (64^3 x 32)
            float4 fvv[8];
#pragma unroll
            for (int q = 0; q < 8; ++q) fvv[q] = make_float4(0.f, 0.f, 0.f, 0.f);
            {
                float gfx = fminf(fmaxf((g1x + 1.0f) * 0.5f * 63.0f, 0.0f), 63.0f);
                float gfy = fminf(fmaxf((g1y + 1.0f) * 0.5f * 63.0f, 0.0f), 63.0f);
                float gfz = fminf(fmaxf((g1z + 1.0f) * 0.5f * 63.0f, 0.0f), 63.0f);
                float gx0f = floorf(gfx), gy0f = floorf(gfy), gz0f = floorf(gfz);
                float gwx = gfx - gx0f, gwy = gfy - gy0f, gwz = gfz - gz0f;
                int gx0 = (int)gx0f, gy0 = (int)gy0f, gz0 = (int)gz0f;
                int gx1 = min(gx0 + 1, 63), gy1 = min(gy0 + 1, 63), gz1 = min(gz0 + 1, 63);
                float wz0 = 1.f - gwz, wy0 = 1.f - gwy, wx0 = 1.f - gwx;
#pragma unroll
                for (int cc = 0; cc < 8; ++cc) {
                    int zz = (cc & 4) ? gz1 : gz0;
                    int yy = (cc & 2) ? gy1 : gy0;
                    int xx = (cc & 1) ? gx1 : gx0;
                    float wgt = ((cc & 4) ? gwz : wz0) * ((cc & 2) ? gwy : wy0) * ((cc & 1) ? gwx : wx0);
                    const float4* p = (const float4*)(Fg + (((((zz << 6) | yy) << 6) | xx) << 5));
#pragma unroll
                    for (int q = 0; q < 8; ++q) {
                        float4 v = p[q];
                        fvv[q].x = fmaf(wgt, v.x, fvv[q].x);
                        fvv[q].y = fmaf(wgt, v.y, fvv[q].y);
                        fvv[q].z = fmaf(wgt, v.z, fvv[q].z);
                        fvv[q].w = fmaf(wgt, v.w, fvv[q].w);
                    }
                }
            }

#pragma unroll
            for (int q = 0; q < 4; ++q) {
                uint4 u;
                u.x = pk2(fvv[2 * q].x, fvv[2 * q].y);
                u.y = pk2(fvv[2 * q].z, fvv[2 * q].w);
                u.z = pk2(fvv[2 * q + 1].x, fvv[2 * q + 1].y);
                u.w = pk2(fvv[2 * q + 1].z, fvv[2 * q + 1].w);
                op[q * 32] = u;
            }
        }
    } else {
        const int t = tid - 256;
#pragma unroll
        for (int i = 0; i < 13; ++i) wlds[t + i * 256] = wsg[t + i * 256];  // frags 0..51
    }
    __syncthreads();

    // ================= phase 2: MLP chain (1 wave = 32 samples) =================
    const float ox = rays_o[ray * 3 + 0], oy = rays_o[ray * 3 + 1], oz = rays_o[ray * 3 + 2];
    const float dx = rays_d[ray * 3 + 0], dy = rays_d[ray * 3 + 1], dz = rays_d[ray * 3 + 2];

    float tnear, tmax;
    ray_aabb(ox, oy, oz, dx, dy, dz, tnear, tmax);
    const bool hit = (tmax > tnear);
    const bool dead = !hit || (tnear + (float)cbase * FSTEP >= tmax);  // masked = suffix

    if (dead) {
        if (lane < 32) comp[wr][cbase + lane] = make_float4(0.f, 0.f, 0.f, 0.f);
    } else {
        const f32x16 z16 = {0.f};

        // ---- s0: 32 -> 128 ; B-frags from LDS fv buffer ----
        unsigned p0[32];
        {
            short8 xb[2];
#pragma unroll
            for (int kt = 0; kt < 2; ++kt)
                xb[kt] = *(const short8*)&fvb[w * 128 + (kt * 2 + h) * 32 + c];
#pragma unroll
            for (int nt = 0; nt < 4; ++nt) {
                f32x16 a = z16;
#pragma unroll
                for (int kt = 0; kt < 2; ++kt) {
                    short8 wv = *(const short8*)&wlds[(nt * 2 + kt) * 64 + lane];
                    a = MFMA32(wv, xb[kt], a);
                }
#pragma unroll
                for (int p = 0; p < 8; ++p)
                    p0[nt * 8 + p] = pk2(fmaxf(a[2 * p], 0.f), fmaxf(a[2 * p + 1], 0.f));
            }
        }

        // ---- s1: 128 -> 128 (nt-outer keeps one acc slice live) ----
        unsigned p1[32];
#pragma unroll
        for (int nt = 0; nt < 4; ++nt) {
            f32x16 a = z16;
#pragma unroll
            for (int kt = 0; kt < 8; ++kt) {
                short8 B0;
                BUILD_B(B0, p0, 4 * kt);
                short8 wv = *(const short8*)&wlds[(8 + nt * 8 + kt) * 64 + lane];
                a = MFMA32(wv, B0, a);
            }
#pragma unroll
            for (int p = 0; p < 8; ++p)
                p1[nt * 8 + p] = pk2(fmaxf(a[2 * p], 0.f), fmaxf(a[2 * p + 1], 0.f));
        }

        // ---- s2: 128 -> 16 (raw) ----
        unsigned s2p[4];
        float alphaR;
        {
            f32x16 S = z16;
#pragma unroll
            for (int kt = 0; kt < 8; ++kt) {
                short8 B0;
                BUILD_B(B0, p1, 4 * kt);
                short8 wv = *(const short8*)&wlds[(40 + kt) * 64 + lane];
                S = MFMA32(wv, B0, S);
            }
#pragma unroll
            for (int p = 0; p < 4; ++p) s2p[p] = pk2(S[2 * p], S[2 * p + 1]);
            float tp = tnear + (float)(cbase + c) * FSTEP;
            float sg = fmaxf(S[0], 0.f);
            alphaR = (tp < tmax) ? 1.0f - __expf(-sg * FSTEP) : 0.0f;
        }

        // ---- SH deg-4 enc (computed late to shrink live range) ----
        short8 Benc;
        {
            float inv = rsqrtf(dx * dx + dy * dy + dz * dz);
            float nx = dx * inv, ny = dy * inv, nz = dz * inv;
            float nx2 = nx * nx, ny2 = ny * ny, nz2 = nz * nz;
            float nxy = nx * ny, nyz = ny * nz, nxz = nx * nz;
            float e0 = 0.28209479177387814f;
            float e1 = -0.48860251190291987f * ny;
            float e2 = 0.48860251190291987f * nz;
            float e3 = -0.48860251190291987f * nx;
            float e4 = 1.0925484305920792f * nxy;
            float e5 = -1.0925484305920792f * nyz;
            float e6 = 0.94617469575756f * nz2 - 0.31539156525252f;
            float e7 = -1.0925484305920792f * nxz;
            float e8 = 0.5462742152960396f * (nx2 - ny2);
            float e9 = 0.5900435899266435f * ny * (-3.0f * nx2 + ny2);
            float e10 = 2.890611442640554f * nxy * nz;
            float e11 = 0.4570457994644657f * ny * (1.0f - 5.0f * nz2);
            float e12 = 0.3731763325901154f * nz * (5.0f * nz2 - 3.0f);
            float e13 = 0.4570457994644657f * nx * (1.0f - 5.0f * nz2);
            float e14 = 1.445305721320277f * nz * (nx2 - ny2);
            float e15 = 0.5900435899266435f * nx * (-nx2 + 3.0f * ny2);
            union { unsigned u[4]; short8 v; } bb;
            bb.u[0] = h ? pk2(e8, e9)   : pk2(e0, e1);
            bb.u[1] = h ? pk2(e10, e11) : pk2(e2, e3);
            bb.u[2] = h ? pk2(e12, e13) : pk2(e4, e5);
            bb.u[3] = h ? pk2(e14, e15) : pk2(e6, e7);
            Benc = bb.v;
        }

        // ---- c0: [enc|sig] 32 -> 64 ----
        unsigned c0p[16];
        {
            short8 Bs0;
            BUILD_B(Bs0, s2p, 0);
#pragma unroll
            for (int nt = 0; nt < 2; ++nt) {
                f32x16 a = z16;
                short8 wv0 = *(const short8*)&wlds[(48 + nt * 2 + 0) * 64 + lane];
                a = MFMA32(wv0, Benc, a);
                short8 wv1 = *(const short8*)&wlds[(48 + nt * 2 + 1) * 64 + lane];
                a = MFMA32(wv1, Bs0, a);
#pragma unroll
                for (int p = 0; p < 8; ++p)
                    c0p[nt * 8 + p] = pk2(fmaxf(a[2 * p], 0.f), fmaxf(a[2 * p + 1], 0.f));
            }
        }

        // ---- c1: 64 -> 64 (weights from global, L2-hot) ----
        unsigned c1p[16];
#pragma unroll
        for (int nt = 0; nt < 2; ++nt) {
            f32x16 a = z16;
#pragma unroll
            for (int kt = 0; kt < 4; ++kt) {
                short8 B0;
                BUILD_B(B0, c0p, 4 * kt);
                short8 wv = *(const short8*)&wsg[(52 + nt * 4 + kt) * 64 + lane];
                a = MFMA32(wv, B0, a);
            }
#pragma unroll
            for (int p = 0; p < 8; ++p)
                c1p[nt * 8 + p] = pk2(fmaxf(a[2 * p], 0.f), fmaxf(a[2 * p + 1], 0.f));
        }

        // ---- c2: 64 -> 3 (weights from global, L2-hot) ----
        {
            f32x16 F = z16;
#pragma unroll
            for (int kt = 0; kt < 4; ++kt) {
                short8 B0;
                BUILD_B(B0, c1p, 4 * kt);
                short8 wv = *(const short8*)&wsg[(60 + kt) * 64 + lane];
                F = MFMA32(wv, B0, F);
            }
            if (h == 0) {  // rows n=0,1,2 live on half 0, regs 0..2
                float4 cv;
                cv.x = alphaR;
                cv.y = 1.0f / (1.0f + __expf(-F[0]));
                cv.z = 1.0f / (1.0f + __expf(-F[1]));
                cv.w = 1.0f / (1.0f + __expf(-F[2]));
                comp[wr][cbase + c] = cv;
            }
        }
    }

    __syncthreads();

    // ================= phase 3: composite (waves 0,1 each scan one ray) =================
    if (tid < 128) {
        const int cr = tid >> 6;   // local ray 0/1
        const int ln = tid & 63;
        float4 vl = comp[cr][ln];
        float4 vh = comp[cr][ln + 64];
        float a_lo = vl.x, a_hi = vh.x;
        float m_lo = 1.0f - a_lo + 1e-10f;
        float m_hi = 1.0f - a_hi + 1e-10f;

        float p = m_lo;
#pragma unroll
        for (int off = 1; off < 64; off <<= 1) {
            float q = __shfl_up(p, off, 64);
            if (ln >= off) p *= q;
        }
        float ph = m_hi;
#pragma unroll
        for (int off = 1; off < 64; off <<= 1) {
            float q = __shfl_up(ph, off, 64);
            if (ln >= off) ph *= q;
        }
        float total_lo = __shfl(p, 63, 64);
        float e_lo = __shfl_up(p, 1, 64);
        if (ln == 0) e_lo = 1.0f;
        float e_hi = __shfl_up(ph, 1, 64);
        if (ln == 0) e_hi = 1.0f;
        e_hi *= total_lo;

        float w_lo = a_lo * e_lo;
        float w_hi = a_hi * e_hi;

        float sr = w_lo * vl.y + w_hi * vh.y;
        float sg = w_lo * vl.z + w_hi * vh.z;
        float sb = w_lo * vl.w + w_hi * vh.w;
        float sw = w_lo + w_hi;
#pragma unroll
        for (int off = 32; off >= 1; off >>= 1) {
            sr += __shfl_xor(sr, off, 64);
            sg += __shfl_xor(sg, off, 64);
            sb += __shfl_xor(sb, off, 64);
            sw += __shfl_xor(sw, off, 64);
        }
        if (ln == 0) {
            int rg = blockIdx.x * 2 + cr;
            float bg = 1.0f - sw;
            out[rg * 3 + 0] = sr + bg;
            out[rg * 3 + 1] = sg + bg;
            out[rg * 3 + 2] = sb + bg;
        }
    }
}

extern "C" void kernel_launch(void* const* d_in, const int* in_sizes, int n_in,
                              void* d_out, int out_size, void* d_ws, size_t ws_size,
                              hipStream_t stream) {
    const float* rays_o = (const float*)d_in[0];
    const float* rays_d = (const float*)d_in[1];
    const float* G1 = (const float*)d_in[2];
    const float* Fg = (const float*)d_in[3];
    const float* s_w0 = (const float*)d_in[4];
    const float* s_w1 = (const float*)d_in[5];
    const float* s_w2 = (const float*)d_in[6];
    const float* c_w0 = (const float*)d_in[7];
    const float* c_w1 = (const float*)d_in[8];
    const float* c_w2 = (const float*)d_in[9];
    float* out = (float*)d_out;

    const int B = in_sizes[0] / 3;  // 8192 rays

    if (ws_size < 65536) return;  // observed ws_size ~805 MB; need 64 KB for weight frags

    prep_weights_kernel<<<dim3(64), dim3(64), 0, stream>>>(s_w0, s_w1, s_w2, c_w0, c_w1, c_w2,
                                                           (uint4*)d_ws);
    fused_kernel<<<dim3(B / 2), dim3(512), 0, stream>>>(rays_o, rays_d, G1, Fg,
                                                        (const uint4*)d_ws, out);
}

// Round 10
// 107.876 us; speedup vs baseline: 1.0263x; 1.0263x over previous
//
#include <hip/hip_runtime.h>
#include <hip/hip_bf16.h>

#define FRADIUS 1.3f
#define FSTEP (2.0f * 1.3f / 128.0f)

typedef __attribute__((ext_vector_type(8))) short short8;
typedef __attribute__((ext_vector_type(16))) float f32x16;

#define MFMA32(a, b, c) __builtin_amdgcn_mfma_f32_32x32x16_bf16((a), (b), (c), 0, 0, 0)

// pack two f32 -> bf16x2 in a dword (RNE); low 16 bits = a
__device__ __forceinline__ unsigned pk2(float a, float b) {
    __hip_bfloat162 hh = __float22bfloat162_rn(make_float2(a, b));
    union { __hip_bfloat162 h; unsigned u; } cv;
    cv.h = hh;
    return cv.u;
}

__device__ __forceinline__ void ray_aabb(float ox, float oy, float oz,
                                         float dx, float dy, float dz,
                                         float& tnear, float& tmax) {
    float sdx = (fabsf(dx) < 1e-9f) ? 1e-9f : dx;
    float sdy = (fabsf(dy) < 1e-9f) ? 1e-9f : dy;
    float sdz = (fabsf(dz) < 1e-9f) ? 1e-9f : dz;
    float t1x = (-FRADIUS - ox) / sdx, t2x = (FRADIUS - ox) / sdx;
    float t1y = (-FRADIUS - oy) / sdy, t2y = (FRADIUS - oy) / sdy;
    float t1z = (-FRADIUS - oz) / sdz, t2z = (FRADIUS - oz) / sdz;
    float tmin = fmaxf(fmaxf(fminf(t1x, t2x), fminf(t1y, t2y)), fminf(t1z, t2z));
    tmax = fminf(fminf(fmaxf(t1x, t2x), fmaxf(t1y, t2y)), fmaxf(t1z, t2z));
    tnear = fmaxf(tmin, 0.0f);
}

// ---------------- weight prep: 32x32x16 A-frags (lane l: A[m=l&31][k=(l>>5)*8+j]) ----------------
// fid map: s0(32->128): 0..7 = nt*2+kt | s1(128->128): 8..39 = 8+nt*8+kt | s2(128->16pad32): 40..47 = 40+kt
//          c0(32->64): 48..51 = 48+nt*2+kt | c1(64->64): 52..59 = 52+nt*4+kt | c2(64->3pad32): 60..63 = 60+kt
__global__ void prep_weights_kernel(const float* __restrict__ s_w0, const float* __restrict__ s_w1,
                                    const float* __restrict__ s_w2, const float* __restrict__ c_w0,
                                    const float* __restrict__ c_w1, const float* __restrict__ c_w2,
                                    uint4* __restrict__ ws) {
    int fid = blockIdx.x;   // 64 frags
    int l = threadIdx.x;    // 64 lanes
    int h = l >> 5, m = l & 31;
    int layer, nt = 0, kt = 0;
    if (fid < 8)       { layer = 0; nt = fid >> 1; kt = fid & 1; }
    else if (fid < 40) { layer = 1; int f = fid - 8;  nt = f >> 3; kt = f & 7; }
    else if (fid < 48) { layer = 2; kt = fid - 40; }
    else if (fid < 52) { layer = 3; int f = fid - 48; nt = f >> 1; kt = f & 1; }
    else if (fid < 60) { layer = 4; int f = fid - 52; nt = f >> 2; kt = f & 3; }
    else               { layer = 5; kt = fid - 60; }
    int n = nt * 32 + m;
    float v[8];
#pragma unroll
    for (int j = 0; j < 8; ++j) {
        int k = kt * 16 + h * 8 + j;
        float x;
        if (layer == 0)      x = s_w0[k * 128 + n];
        else if (layer == 1) x = s_w1[k * 128 + n];
        else if (layer == 2) x = (n < 16) ? s_w2[k * 16 + n] : 0.0f;
        else if (layer == 3) x = (k < 16) ? c_w0[k * 64 + n]
                                 : ((k == 16) ? 0.0f : c_w0[(k - 1) * 64 + n]);  // zero row: sigma unused
        else if (layer == 4) x = c_w1[k * 64 + n];
        else                 x = (n < 3) ? c_w2[k * 3 + n] : 0.0f;
        v[j] = x;
    }
    uint4 u;
    u.x = pk2(v[0], v[1]); u.y = pk2(v[2], v[3]);
    u.z = pk2(v[4], v[5]); u.w = pk2(v[6], v[7]);
    ws[fid * 64 + l] = u;
}

// ---------------- kernel A: gather (1 thread = 1 sample point) ----------------
// output layout: per 32-sample group g: [kt(2)][h(2)][s32(32)] x uint4 (B-frag-ready)
__global__ __launch_bounds__(256) void sample_kernel(
    const float* __restrict__ rays_o, const float* __restrict__ rays_d,
    const float* __restrict__ G1, const float* __restrict__ Fg,
    uint4* __restrict__ fvout) {
    const int idx = blockIdx.x * 256 + threadIdx.x;
    const int ray = idx >> 7;
    const int s = idx & 127;

    const float ox = rays_o[ray * 3 + 0], oy = rays_o[ray * 3 + 1], oz = rays_o[ray * 3 + 2];
    const float dx = rays_d[ray * 3 + 0], dy = rays_d[ray * 3 + 1], dz = rays_d[ray * 3 + 2];

    float tnear, tmax;
    ray_aabb(ox, oy, oz, dx, dy, dz, tnear, tmax);
    float t = tnear + (float)s * FSTEP;
    bool maskb = (t < tmax) && (tmax > tnear);

    uint4* op = fvout + (size_t)(idx >> 5) * 128 + (idx & 31);
    if (!maskb) {
        uint4 z = {0u, 0u, 0u, 0u};
#pragma unroll
        for (int q = 0; q < 4; ++q) op[q * 32] = z;
        return;
    }

    float px = ox + dx * t, py = oy + dy * t, pz = oz + dz * t;
    const float invR = 1.0f / FRADIUS;
    float cx = px * invR, cy = py * invR, cz = pz * invR;

    // G1 trilinear (256^3 x 3)
    float fx = fminf(fmaxf((cx + 1.0f) * 0.5f * 255.0f, 0.0f), 255.0f);
    float fy = fminf(fmaxf((cy + 1.0f) * 0.5f * 255.0f, 0.0f), 255.0f);
    float fz = fminf(fmaxf((cz + 1.0f) * 0.5f * 255.0f, 0.0f), 255.0f);
    float x0f = floorf(fx), y0f = floorf(fy), z0f = floorf(fz);
    float wx = fx - x0f, wy = fy - y0f, wz = fz - z0f;
    int x0 = (int)x0f, y0 = (int)y0f, z0 = (int)z0f;
    int x1 = min(x0 + 1, 255), y1 = min(y0 + 1, 255), z1 = min(z0 + 1, 255);
    float g1x = 0.f, g1y = 0.f, g1z = 0.f;
    {
        float wz0 = 1.f - wz, wy0 = 1.f - wy, wx0 = 1.f - wx;
#pragma unroll
        for (int cc = 0; cc < 8; ++cc) {
            int zz = (cc & 4) ? z1 : z0;
            int yy = (cc & 2) ? y1 : y0;
            int xx = (cc & 1) ? x1 : x0;
            float wgt = ((cc & 4) ? wz : wz0) * ((cc & 2) ? wy : wy0) * ((cc & 1) ? wx : wx0);
            int gidx = (((zz << 8) | yy) << 8 | xx) * 3;
            g1x = fmaf(wgt, G1[gidx + 0], g1x);
            g1y = fmaf(wgt, G1[gidx + 1], g1y);
            g1z = fmaf(wgt, G1[gidx + 2], g1z);
        }
    }

    // Fg trilinear (64^3 x 32)
    float4 fvv[8];
#pragma unroll
    for (int q = 0; q < 8; ++q) fvv[q] = make_float4(0.f, 0.f, 0.f, 0.f);
    {
        float gfx = fminf(fmaxf((g1x + 1.0f) * 0.5f * 63.0f, 0.0f), 63.0f);
        float gfy = fminf(fmaxf((g1y + 1.0f) * 0.5f * 63.0f, 0.0f), 63.0f);
        float gfz = fminf(fmaxf((g1z + 1.0f) * 0.5f * 63.0f, 0.0f), 63.0f);
        float gx0f = floorf(gfx), gy0f = floorf(gfy), gz0f = floorf(gfz);
        float gwx = gfx - gx0f, gwy = gfy - gy0f, gwz = gfz - gz0f;
        int gx0 = (int)gx0f, gy0 = (int)gy0f, gz0 = (int)gz0f;
        int gx1 = min(gx0 + 1, 63), gy1 = min(gy0 + 1, 63), gz1 = min(gz0 + 1, 63);
        float wz0 = 1.f - gwz, wy0 = 1.f - gwy, wx0 = 1.f - gwx;
#pragma unroll
        for (int cc = 0; cc < 8; ++cc) {
            int zz = (cc & 4) ? gz1 : gz0;
            int yy = (cc & 2) ? gy1 : gy0;
            int xx = (cc & 1) ? gx1 : gx0;
            float wgt = ((cc & 4) ? gwz : wz0) * ((cc & 2) ? gwy : wy0) * ((cc & 1) ? gwx : wx0);
            const float4* p = (const float4*)(Fg + (((((zz << 6) | yy) << 6) | xx) << 5));
#pragma unroll
            for (int q = 0; q < 8; ++q) {
                float4 v = p[q];
                fvv[q].x = fmaf(wgt, v.x, fvv[q].x);
                fvv[q].y = fmaf(wgt, v.y, fvv[q].y);
                fvv[q].z = fmaf(wgt, v.z, fvv[q].z);
                fvv[q].w = fmaf(wgt, v.w, fvv[q].w);
            }
        }
    }

#pragma unroll
    for (int q = 0; q < 4; ++q) {
        uint4 u;
        u.x = pk2(fvv[2 * q].x, fvv[2 * q].y);
        u.y = pk2(fvv[2 * q].z, fvv[2 * q].w);
        u.z = pk2(fvv[2 * q + 1].x, fvv[2 * q + 1].y);
        u.w = pk2(fvv[2 * q + 1].z, fvv[2 * q + 1].w);
        op[q * 32] = u;
    }
}

// Build next-layer B-frag from packed activations PK (per-lane dword array, static idx only).
// Derivation (validated r5-r9): target dword u of lane (h,c): pd = BASE + 2h + (u&1), source half = u>>1.
#define BUILD_B(B, PK, BASE) do {                                         \
    unsigned own0 = h ? (PK)[(BASE) + 2] : (PK)[(BASE) + 0];              \
    unsigned own1 = h ? (PK)[(BASE) + 3] : (PK)[(BASE) + 1];              \
    unsigned snd0 = h ? (PK)[(BASE) + 0] : (PK)[(BASE) + 2];              \
    unsigned snd1 = h ? (PK)[(BASE) + 1] : (PK)[(BASE) + 3];              \
    unsigned r0 = (unsigned)__shfl_xor((int)snd0, 32, 64);                \
    unsigned r1 = (unsigned)__shfl_xor((int)snd1, 32, 64);                \
    union { unsigned u[4]; short8 v; } bb;                                \
    bb.u[0] = h ? r0 : own0;  bb.u[1] = h ? r1 : own1;                    \
    bb.u[2] = h ? own0 : r0;  bb.u[3] = h ? own1 : r1;                    \
    (B) = bb.v; } while (0)

// ---------------- kernel B: 32x32x16 MLP, 1 tile (32 samples) per wave ----------------
// block = 512 thd = 8 waves = 8 chunks = 2 rays. wave w: ray = 2*blk + (w>>2), chunk = w&3.
// B-frags for the NEXT layer are built ONCE right after each layer's pack (frag precompute),
// so the MFMA inner loops are pure {ds_read, MFMA} with no cross-lane ops.
// LDS = 64 KB weights + 4 KB comp = 68 KB -> 2 blocks/CU; VGPR cap 128 (4 waves/EU).
__global__ __launch_bounds__(512, 4) void mlp_kernel7(
    const float* __restrict__ rays_o, const float* __restrict__ rays_d,
    const uint4* __restrict__ wsg, const short8* __restrict__ fvin,
    float* __restrict__ out) {

    __shared__ uint4 wlds[64 * 64];    // 64 KiB: 64 frags x 64 lanes x 16 B
    __shared__ float4 comp[2][128];

    const int tid = threadIdx.x;
    const int w = tid >> 6;           // 0..7
    const int lane = tid & 63;
    const int h = lane >> 5;
    const int c = lane & 31;
    const int wr = w >> 2;            // local ray 0/1
    const int chunk = w & 3;          // 32-sample chunk within ray
    const int ray = blockIdx.x * 2 + wr;
    const int cbase = chunk * 32;

    // ---- stage all weight frags into LDS (coalesced, one-time) ----
#pragma unroll
    for (int i = 0; i < 8; ++i) wlds[tid + i * 512] = wsg[tid + i * 512];
    __syncthreads();

    const float ox = rays_o[ray * 3 + 0], oy = rays_o[ray * 3 + 1], oz = rays_o[ray * 3 + 2];
    const float dx = rays_d[ray * 3 + 0], dy = rays_d[ray * 3 + 1], dz = rays_d[ray * 3 + 2];

    float tnear, tmax;
    ray_aabb(ox, oy, oz, dx, dy, dz, tnear, tmax);
    const bool hit = (tmax > tnear);
    const bool dead = !hit || (tnear + (float)cbase * FSTEP >= tmax);  // masked = suffix

    if (dead) {
        if (lane < 32) comp[wr][cbase + lane] = make_float4(0.f, 0.f, 0.f, 0.f);
    } else {
        const f32x16 z16 = {0.f};

        // ---- s0: 32 -> 128 ; outputs emitted directly as next-layer B-frags b0f[8] ----
        short8 b0f[8];
        {
            short8 xb[2];
            const int g = ray * 4 + chunk;
#pragma unroll
            for (int kt = 0; kt < 2; ++kt)
                xb[kt] = fvin[(size_t)g * 128 + (kt * 2 + h) * 32 + c];
#pragma unroll
            for (int nt = 0; nt < 4; ++nt) {
                f32x16 a = z16;
#pragma unroll
                for (int kt = 0; kt < 2; ++kt) {
                    short8 wv = *(const short8*)&wlds[(nt * 2 + kt) * 64 + lane];
                    a = MFMA32(wv, xb[kt], a);
                }
                unsigned pkt[8];
#pragma unroll
                for (int p = 0; p < 8; ++p)
                    pkt[p] = pk2(fmaxf(a[2 * p], 0.f), fmaxf(a[2 * p + 1], 0.f));
                BUILD_B(b0f[2 * nt + 0], pkt, 0);
                BUILD_B(b0f[2 * nt + 1], pkt, 4);
            }
        }

        // ---- s1: 128 -> 128 (inner loop is pure {ds_read, MFMA}) ----
        short8 b1f[8];
#pragma unroll
        for (int nt = 0; nt < 4; ++nt) {
            f32x16 a = z16;
#pragma unroll
            for (int kt = 0; kt < 8; ++kt) {
                short8 wv = *(const short8*)&wlds[(8 + nt * 8 + kt) * 64 + lane];
                a = MFMA32(wv, b0f[kt], a);
            }
            unsigned pkt[8];
#pragma unroll
            for (int p = 0; p < 8; ++p)
                pkt[p] = pk2(fmaxf(a[2 * p], 0.f), fmaxf(a[2 * p + 1], 0.f));
            BUILD_B(b1f[2 * nt + 0], pkt, 0);
            BUILD_B(b1f[2 * nt + 1], pkt, 4);
        }

        // ---- s2: 128 -> 16 (raw); sig output emitted as B-frag Bsig ----
        short8 Bsig;
        float alphaR;
        {
            f32x16 S = z16;
#pragma unroll
            for (int kt = 0; kt < 8; ++kt) {
                short8 wv = *(const short8*)&wlds[(40 + kt) * 64 + lane];
                S = MFMA32(wv, b1f[kt], S);
            }
            unsigned s2p[4];
#pragma unroll
            for (int p = 0; p < 4; ++p) s2p[p] = pk2(S[2 * p], S[2 * p + 1]);
            BUILD_B(Bsig, s2p, 0);
            float tp = tnear + (float)(cbase + c) * FSTEP;
            float sg = fmaxf(S[0], 0.f);
            alphaR = (tp < tmax) ? 1.0f - __expf(-sg * FSTEP) : 0.0f;
        }

        // ---- SH deg-4 enc (computed late to shrink live range) ----
        short8 Benc;
        {
            float inv = rsqrtf(dx * dx + dy * dy + dz * dz);
            float nx = dx * inv, ny = dy * inv, nz = dz * inv;
            float nx2 = nx * nx, ny2 = ny * ny, nz2 = nz * nz;
            float nxy = nx * ny, nyz = ny * nz, nxz = nx * nz;
            float e0 = 0.28209479177387814f;
            float e1 = -0.48860251190291987f * ny;
            float e2 = 0.48860251190291987f * nz;
            float e3 = -0.48860251190291987f * nx;
            float e4 = 1.0925484305920792f * nxy;
            float e5 = -1.0925484305920792f * nyz;
            float e6 = 0.94617469575756f * nz2 - 0.31539156525252f;
            float e7 = -1.0925484305920792f * nxz;
            float e8 = 0.5462742152960396f * (nx2 - ny2);
            float e9 = 0.5900435899266435f * ny * (-3.0f * nx2 + ny2);
            float e10 = 2.890611442640554f * nxy * nz;
            float e11 = 0.4570457994644657f * ny * (1.0f - 5.0f * nz2);
            float e12 = 0.3731763325901154f * nz * (5.0f * nz2 - 3.0f);
            float e13 = 0.4570457994644657f * nx * (1.0f - 5.0f * nz2);
            float e14 = 1.445305721320277f * nz * (nx2 - ny2);
            float e15 = 0.5900435899266435f * nx * (-nx2 + 3.0f * ny2);
            union { unsigned u[4]; short8 v; } bb;
            bb.u[0] = h ? pk2(e8, e9)   : pk2(e0, e1);
            bb.u[1] = h ? pk2(e10, e11) : pk2(e2, e3);
            bb.u[2] = h ? pk2(e12, e13) : pk2(e4, e5);
            bb.u[3] = h ? pk2(e14, e15) : pk2(e6, e7);
            Benc = bb.v;
        }

        // ---- c0: [enc|sig] 32 -> 64 ; outputs emitted as B-frags c0f[4] ----
        short8 c0f[4];
#pragma unroll
        for (int nt = 0; nt < 2; ++nt) {
            f32x16 a = z16;
            short8 wv0 = *(const short8*)&wlds[(48 + nt * 2 + 0) * 64 + lane];
            a = MFMA32(wv0, Benc, a);
            short8 wv1 = *(const short8*)&wlds[(48 + nt * 2 + 1) * 64 + lane];
            a = MFMA32(wv1, Bsig, a);
            unsigned pkt[8];
#pragma unroll
            for (int p = 0; p < 8; ++p)
                pkt[p] = pk2(fmaxf(a[2 * p], 0.f), fmaxf(a[2 * p + 1], 0.f));
            BUILD_B(c0f[2 * nt + 0], pkt, 0);
            BUILD_B(c0f[2 * nt + 1], pkt, 4);
        }

        // ---- c1: 64 -> 64 ----
        short8 c1f[4];
#pragma unroll
        for (int nt = 0; nt < 2; ++nt) {
            f32x16 a = z16;
#pragma unroll
            for (int kt = 0; kt < 4; ++kt) {
                short8 wv = *(const short8*)&wlds[(52 + nt * 4 + kt) * 64 + lane];
                a = MFMA32(wv, c0f[kt], a);
            }
            unsigned pkt[8];
#pragma unroll
            for (int p = 0; p < 8; ++p)
                pkt[p] = pk2(fmaxf(a[2 * p], 0.f), fmaxf(a[2 * p + 1], 0.f));
            BUILD_B(c1f[2 * nt + 0], pkt, 0);
            BUILD_B(c1f[2 * nt + 1], pkt, 4);
        }

        // ---- c2: 64 -> 3 ----
        {
            f32x16 F = z16;
#pragma unroll
            for (int kt = 0; kt < 4; ++kt) {
                short8 wv = *(const short8*)&wlds[(60 + kt) * 64 + lane];
                F = MFMA32(wv, c1f[kt], F);
            }
            if (h == 0) {  // rows n=0,1,2 live on half 0, regs 0..2
                float4 cv;
                cv.x = alphaR;
                cv.y = 1.0f / (1.0f + __expf(-F[0]));
                cv.z = 1.0f / (1.0f + __expf(-F[1]));
                cv.w = 1.0f / (1.0f + __expf(-F[2]));
                comp[wr][cbase + c] = cv;
            }
        }
    }

    __syncthreads();

    // ---- composite: waves 0,1 each scan one ray ----
    if (tid < 128) {
        const int cr = tid >> 6;   // local ray 0/1
        const int ln = tid & 63;
        float4 vl = comp[cr][ln];
        float4 vh = comp[cr][ln + 64];
        float a_lo = vl.x, a_hi = vh.x;
        float m_lo = 1.0f - a_lo + 1e-10f;
        float m_hi = 1.0f - a_hi + 1e-10f;

        float p = m_lo;
#pragma unroll
        for (int off = 1; off < 64; off <<= 1) {
            float q = __shfl_up(p, off, 64);
            if (ln >= off) p *= q;
        }
        float ph = m_hi;
#pragma unroll
        for (int off = 1; off < 64; off <<= 1) {
            float q = __shfl_up(ph, off, 64);
            if (ln >= off) ph *= q;
        }
        float total_lo = __shfl(p, 63, 64);
        float e_lo = __shfl_up(p, 1, 64);
        if (ln == 0) e_lo = 1.0f;
        float e_hi = __shfl_up(ph, 1, 64);
        if (ln == 0) e_hi = 1.0f;
        e_hi *= total_lo;

        float w_lo = a_lo * e_lo;
        float w_hi = a_hi * e_hi;

        float sr = w_lo * vl.y + w_hi * vh.y;
        float sg = w_lo * vl.z + w_hi * vh.z;
        float sb = w_lo * vl.w + w_hi * vh.w;
        float sw = w_lo + w_hi;
#pragma unroll
        for (int off = 32; off >= 1; off >>= 1) {
            sr += __shfl_xor(sr, off, 64);
            sg += __shfl_xor(sg, off, 64);
            sb += __shfl_xor(sb, off, 64);
            sw += __shfl_xor(sw, off, 64);
        }
        if (ln == 0) {
            int rg = blockIdx.x * 2 + cr;
            float bg = 1.0f - sw;
            out[rg * 3 + 0] = sr + bg;
            out[rg * 3 + 1] = sg + bg;
            out[rg * 3 + 2] = sb + bg;
        }
    }
}

extern "C" void kernel_launch(void* const* d_in, const int* in_sizes, int n_in,
                              void* d_out, int out_size, void* d_ws, size_t ws_size,
                              hipStream_t stream) {
    const float* rays_o = (const float*)d_in[0];
    const float* rays_d = (const float*)d_in[1];
    const float* G1 = (const float*)d_in[2];
    const float* Fg = (const float*)d_in[3];
    const float* s_w0 = (const float*)d_in[4];
    const float* s_w1 = (const float*)d_in[5];
    const float* s_w2 = (const float*)d_in[6];
    const float* c_w0 = (const float*)d_in[7];
    const float* c_w1 = (const float*)d_in[8];
    const float* c_w2 = (const float*)d_in[9];
    float* out = (float*)d_out;

    const int B = in_sizes[0] / 3;  // 8192 rays
    const int npts = B * 128;

    const size_t FV_OFF = 65536;
    const size_t need = FV_OFF + (size_t)npts * 64;
    if (ws_size < need) return;  // observed ws_size ~805 MB >> 84 MB needed

    uint4* fv = (uint4*)((char*)d_ws + FV_OFF);

    prep_weights_kernel<<<dim3(64), dim3(64), 0, stream>>>(s_w0, s_w1, s_w2, c_w0, c_w1, c_w2,
                                                           (uint4*)d_ws);
    sample_kernel<<<dim3(npts / 256), dim3(256), 0, stream>>>(rays_o, rays_d, G1, Fg, fv);
    mlp_kernel7<<<dim3(B / 2), dim3(512), 0, stream>>>(rays_o, rays_d, (const uint4*)d_ws,
                                                       (const short8*)fv, out);
}

// Round 11
// 107.870 us; speedup vs baseline: 1.0263x; 1.0001x over previous
//
#include <hip/hip_runtime.h>
#include <hip/hip_bf16.h>

#define FRADIUS 1.3f
#define FSTEP (2.0f * 1.3f / 128.0f)

typedef __attribute__((ext_vector_type(8))) short short8;
typedef __attribute__((ext_vector_type(16))) float f32x16;

#define MFMA32(a, b, c) __builtin_amdgcn_mfma_f32_32x32x16_bf16((a), (b), (c), 0, 0, 0)

// pack two f32 -> bf16x2 in a dword (RNE); low 16 bits = a
__device__ __forceinline__ unsigned pk2(float a, float b) {
    __hip_bfloat162 hh = __float22bfloat162_rn(make_float2(a, b));
    union { __hip_bfloat162 h; unsigned u; } cv;
    cv.h = hh;
    return cv.u;
}

__device__ __forceinline__ void ray_aabb(float ox, float oy, float oz,
                                         float dx, float dy, float dz,
                                         float& tnear, float& tmax) {
    float sdx = (fabsf(dx) < 1e-9f) ? 1e-9f : dx;
    float sdy = (fabsf(dy) < 1e-9f) ? 1e-9f : dy;
    float sdz = (fabsf(dz) < 1e-9f) ? 1e-9f : dz;
    float t1x = (-FRADIUS - ox) / sdx, t2x = (FRADIUS - ox) / sdx;
    float t1y = (-FRADIUS - oy) / sdy, t2y = (FRADIUS - oy) / sdy;
    float t1z = (-FRADIUS - oz) / sdz, t2z = (FRADIUS - oz) / sdz;
    float tmin = fmaxf(fmaxf(fminf(t1x, t2x), fminf(t1y, t2y)), fminf(t1z, t2z));
    tmax = fminf(fminf(fmaxf(t1x, t2x), fmaxf(t1y, t2y)), fmaxf(t1z, t2z));
    tnear = fmaxf(tmin, 0.0f);
}

// ---------------- weight prep: 32x32x16 A-frags (lane l: A[m=l&31][k=(l>>5)*8+j]) ----------------
// fid map: s0(32->128): 0..7 = nt*2+kt | s1(128->128): 8..39 = 8+nt*8+kt | s2(128->16pad32): 40..47 = 40+kt
//          c0(32->64): 48..51 = 48+nt*2+kt | c1(64->64): 52..59 = 52+nt*4+kt | c2(64->3pad32): 60..63 = 60+kt
__global__ void prep_weights_kernel(const float* __restrict__ s_w0, const float* __restrict__ s_w1,
                                    const float* __restrict__ s_w2, const float* __restrict__ c_w0,
                                    const float* __restrict__ c_w1, const float* __restrict__ c_w2,
                                    uint4* __restrict__ ws) {
    int fid = blockIdx.x;   // 64 frags
    int l = threadIdx.x;    // 64 lanes
    int h = l >> 5, m = l & 31;
    int layer, nt = 0, kt = 0;
    if (fid < 8)       { layer = 0; nt = fid >> 1; kt = fid & 1; }
    else if (fid < 40) { layer = 1; int f = fid - 8;  nt = f >> 3; kt = f & 7; }
    else if (fid < 48) { layer = 2; kt = fid - 40; }
    else if (fid < 52) { layer = 3; int f = fid - 48; nt = f >> 1; kt = f & 1; }
    else if (fid < 60) { layer = 4; int f = fid - 52; nt = f >> 2; kt = f & 3; }
    else               { layer = 5; kt = fid - 60; }
    int n = nt * 32 + m;
    float v[8];
#pragma unroll
    for (int j = 0; j < 8; ++j) {
        int k = kt * 16 + h * 8 + j;
        float x;
        if (layer == 0)      x = s_w0[k * 128 + n];
        else if (layer == 1) x = s_w1[k * 128 + n];
        else if (layer == 2) x = (n < 16) ? s_w2[k * 16 + n] : 0.0f;
        else if (layer == 3) x = (k < 16) ? c_w0[k * 64 + n]
                                 : ((k == 16) ? 0.0f : c_w0[(k - 1) * 64 + n]);  // zero row: sigma unused
        else if (layer == 4) x = c_w1[k * 64 + n];
        else                 x = (n < 3) ? c_w2[k * 3 + n] : 0.0f;
        v[j] = x;
    }
    uint4 u;
    u.x = pk2(v[0], v[1]); u.y = pk2(v[2], v[3]);
    u.z = pk2(v[4], v[5]); u.w = pk2(v[6], v[7]);
    ws[fid * 64 + l] = u;
}

// ---------------- kernel A: gather (1 thread = 1 sample point) ----------------
// output layout: per 32-sample group g: [kt(2)][h(2)][s32(32)] x uint4 (B-frag-ready)
__global__ __launch_bounds__(256) void sample_kernel(
    const float* __restrict__ rays_o, const float* __restrict__ rays_d,
    const float* __restrict__ G1, const float* __restrict__ Fg,
    uint4* __restrict__ fvout) {
    const int idx = blockIdx.x * 256 + threadIdx.x;
    const int ray = idx >> 7;
    const int s = idx & 127;

    const float ox = rays_o[ray * 3 + 0], oy = rays_o[ray * 3 + 1], oz = rays_o[ray * 3 + 2];
    const float dx = rays_d[ray * 3 + 0], dy = rays_d[ray * 3 + 1], dz = rays_d[ray * 3 + 2];

    float tnear, tmax;
    ray_aabb(ox, oy, oz, dx, dy, dz, tnear, tmax);
    float t = tnear + (float)s * FSTEP;
    bool maskb = (t < tmax) && (tmax > tnear);

    uint4* op = fvout + (size_t)(idx >> 5) * 128 + (idx & 31);
    if (!maskb) {
        uint4 z = {0u, 0u, 0u, 0u};
#pragma unroll
        for (int q = 0; q < 4; ++q) op[q * 32] = z;
        return;
    }

    float px = ox + dx * t, py = oy + dy * t, pz = oz + dz * t;
    const float invR = 1.0f / FRADIUS;
    float cx = px * invR, cy = py * invR, cz = pz * invR;

    // G1 trilinear (256^3 x 3)
    float fx = fminf(fmaxf((cx + 1.0f) * 0.5f * 255.0f, 0.0f), 255.0f);
    float fy = fminf(fmaxf((cy + 1.0f) * 0.5f * 255.0f, 0.0f), 255.0f);
    float fz = fminf(fmaxf((cz + 1.0f) * 0.5f * 255.0f, 0.0f), 255.0f);
    float x0f = floorf(fx), y0f = floorf(fy), z0f = floorf(fz);
    float wx = fx - x0f, wy = fy - y0f, wz = fz - z0f;
    int x0 = (int)x0f, y0 = (int)y0f, z0 = (int)z0f;
    int x1 = min(x0 + 1, 255), y1 = min(y0 + 1, 255), z1 = min(z0 + 1, 255);
    float g1x = 0.f, g1y = 0.f, g1z = 0.f;
    {
        float wz0 = 1.f - wz, wy0 = 1.f - wy, wx0 = 1.f - wx;
#pragma unroll
        for (int cc = 0; cc < 8; ++cc) {
            int zz = (cc & 4) ? z1 : z0;
            int yy = (cc & 2) ? y1 : y0;
            int xx = (cc & 1) ? x1 : x0;
            float wgt = ((cc & 4) ? wz : wz0) * ((cc & 2) ? wy : wy0) * ((cc & 1) ? wx : wx0);
            int gidx = (((zz << 8) | yy) << 8 | xx) * 3;
            g1x = fmaf(wgt, G1[gidx + 0], g1x);
            g1y = fmaf(wgt, G1[gidx + 1], g1y);
            g1z = fmaf(wgt, G1[gidx + 2], g1z);
        }
    }

    // Fg trilinear (64^3 x 32)
    float4 fvv[8];
#pragma unroll
    for (int q = 0; q < 8; ++q) fvv[q] = make_float4(0.f, 0.f, 0.f, 0.f);
    {
        float gfx = fminf(fmaxf((g1x + 1.0f) * 0.5f * 63.0f, 0.0f), 63.0f);
        float gfy = fminf(fmaxf((g1y + 1.0f) * 0.5f * 63.0f, 0.0f), 63.0f);
        float gfz = fminf(fmaxf((g1z + 1.0f) * 0.5f * 63.0f, 0.0f), 63.0f);
        float gx0f = floorf(gfx), gy0f = floorf(gfy), gz0f = floorf(gfz);
        float gwx = gfx - gx0f, gwy = gfy - gy0f, gwz = gfz - gz0f;
        int gx0 = (int)gx0f, gy0 = (int)gy0f, gz0 = (int)gz0f;
        int gx1 = min(gx0 + 1, 63), gy1 = min(gy0 + 1, 63), gz1 = min(gz0 + 1, 63);
        float wz0 = 1.f - gwz, wy0 = 1.f - gwy, wx0 = 1.f - gwx;
#pragma unroll
        for (int cc = 0; cc < 8; ++cc) {
            int zz = (cc & 4) ? gz1 : gz0;
            int yy = (cc & 2) ? gy1 : gy0;
            int xx = (cc & 1) ? gx1 : gx0;
            float wgt = ((cc & 4) ? gwz : wz0) * ((cc & 2) ? gwy : wy0) * ((cc & 1) ? gwx : wx0);
            const float4* p = (const float4*)(Fg + (((((zz << 6) | yy) << 6) | xx) << 5));
#pragma unroll
            for (int q = 0; q < 8; ++q) {
                float4 v = p[q];
                fvv[q].x = fmaf(wgt, v.x, fvv[q].x);
                fvv[q].y = fmaf(wgt, v.y, fvv[q].y);
                fvv[q].z = fmaf(wgt, v.z, fvv[q].z);
                fvv[q].w = fmaf(wgt, v.w, fvv[q].w);
            }
        }
    }

#pragma unroll
    for (int q = 0; q < 4; ++q) {
        uint4 u;
        u.x = pk2(fvv[2 * q].x, fvv[2 * q].y);
        u.y = pk2(fvv[2 * q].z, fvv[2 * q].w);
        u.z = pk2(fvv[2 * q + 1].x, fvv[2 * q + 1].y);
        u.w = pk2(fvv[2 * q + 1].z, fvv[2 * q + 1].w);
        op[q * 32] = u;
    }
}

// Build next-layer B-frag from packed activations PK (per-lane dword array, static idx only).
// Derivation (validated r5-r10): target dword u of lane (h,c): pd = BASE + 2h + (u&1), source half = u>>1.
#define BUILD_B(B, PK, BASE) do {                                         \
    unsigned own0 = h ? (PK)[(BASE) + 2] : (PK)[(BASE) + 0];              \
    unsigned own1 = h ? (PK)[(BASE) + 3] : (PK)[(BASE) + 1];              \
    unsigned snd0 = h ? (PK)[(BASE) + 0] : (PK)[(BASE) + 2];              \
    unsigned snd1 = h ? (PK)[(BASE) + 1] : (PK)[(BASE) + 3];              \
    unsigned r0 = (unsigned)__shfl_xor((int)snd0, 32, 64);                \
    unsigned r1 = (unsigned)__shfl_xor((int)snd1, 32, 64);                \
    union { unsigned u[4]; short8 v; } bb;                                \
    bb.u[0] = h ? r0 : own0;  bb.u[1] = h ? r1 : own1;                    \
    bb.u[2] = h ? own0 : r0;  bb.u[3] = h ? own1 : r1;                    \
    (B) = bb.v; } while (0)

// ---------------- kernel B: 32x32x16 MLP, 1 tile (32 samples) per wave ----------------
// block = 512 thd = 8 waves = 8 chunks = 2 rays. wave w: ray = 2*blk + (w>>2), chunk = w&3.
// PIPE SPLIT: s0+s1 weights (40 frags = 40 KB) served by the LDS pipe; s2/c0/c1/c2
// (24 frags = 24 KB) served by the vector-memory pipe from L1/L2-resident global —
// balances ~25 µs LDS vs ~23 µs L2 instead of 40 µs all-LDS.
// LDS = 40 KB weights + 4 KB comp = 44 KB; VGPR cap 128 (4 waves/EU).
__global__ __launch_bounds__(512, 4) void mlp_kernel8(
    const float* __restrict__ rays_o, const float* __restrict__ rays_d,
    const uint4* __restrict__ wsg, const short8* __restrict__ fvin,
    float* __restrict__ out) {

    __shared__ uint4 wlds[40 * 64];    // 40 KiB: frags 0..39 (s0 + s1)
    __shared__ float4 comp[2][128];

    const int tid = threadIdx.x;
    const int w = tid >> 6;           // 0..7
    const int lane = tid & 63;
    const int h = lane >> 5;
    const int c = lane & 31;
    const int wr = w >> 2;            // local ray 0/1
    const int chunk = w & 3;          // 32-sample chunk within ray
    const int ray = blockIdx.x * 2 + wr;
    const int cbase = chunk * 32;

    // ---- stage s0+s1 weight frags into LDS (coalesced, one-time) ----
#pragma unroll
    for (int i = 0; i < 5; ++i) wlds[tid + i * 512] = wsg[tid + i * 512];
    __syncthreads();

    const float ox = rays_o[ray * 3 + 0], oy = rays_o[ray * 3 + 1], oz = rays_o[ray * 3 + 2];
    const float dx = rays_d[ray * 3 + 0], dy = rays_d[ray * 3 + 1], dz = rays_d[ray * 3 + 2];

    float tnear, tmax;
    ray_aabb(ox, oy, oz, dx, dy, dz, tnear, tmax);
    const bool hit = (tmax > tnear);
    const bool dead = !hit || (tnear + (float)cbase * FSTEP >= tmax);  // masked = suffix

    if (dead) {
        if (lane < 32) comp[wr][cbase + lane] = make_float4(0.f, 0.f, 0.f, 0.f);
    } else {
        const f32x16 z16 = {0.f};

        // ---- s0: 32 -> 128 ; outputs emitted directly as next-layer B-frags b0f[8] ----
        short8 b0f[8];
        {
            short8 xb[2];
            const int g = ray * 4 + chunk;
#pragma unroll
            for (int kt = 0; kt < 2; ++kt)
                xb[kt] = fvin[(size_t)g * 128 + (kt * 2 + h) * 32 + c];
#pragma unroll
            for (int nt = 0; nt < 4; ++nt) {
                f32x16 a = z16;
#pragma unroll
                for (int kt = 0; kt < 2; ++kt) {
                    short8 wv = *(const short8*)&wlds[(nt * 2 + kt) * 64 + lane];
                    a = MFMA32(wv, xb[kt], a);
                }
                unsigned pkt[8];
#pragma unroll
                for (int p = 0; p < 8; ++p)
                    pkt[p] = pk2(fmaxf(a[2 * p], 0.f), fmaxf(a[2 * p + 1], 0.f));
                BUILD_B(b0f[2 * nt + 0], pkt, 0);
                BUILD_B(b0f[2 * nt + 1], pkt, 4);
            }
        }

        // ---- s1: 128 -> 128 (LDS weights; inner loop pure {ds_read, MFMA}) ----
        short8 b1f[8];
#pragma unroll
        for (int nt = 0; nt < 4; ++nt) {
            f32x16 a = z16;
#pragma unroll
            for (int kt = 0; kt < 8; ++kt) {
                short8 wv = *(const short8*)&wlds[(8 + nt * 8 + kt) * 64 + lane];
                a = MFMA32(wv, b0f[kt], a);
            }
            unsigned pkt[8];
#pragma unroll
            for (int p = 0; p < 8; ++p)
                pkt[p] = pk2(fmaxf(a[2 * p], 0.f), fmaxf(a[2 * p + 1], 0.f));
            BUILD_B(b1f[2 * nt + 0], pkt, 0);
            BUILD_B(b1f[2 * nt + 1], pkt, 4);
        }

        // ---- s2: 128 -> 16 (raw); weights from global (L1/L2-hot) ----
        short8 Bsig;
        float alphaR;
        {
            f32x16 S = z16;
#pragma unroll
            for (int kt = 0; kt < 8; ++kt) {
                short8 wv = *(const short8*)&wsg[(40 + kt) * 64 + lane];
                S = MFMA32(wv, b1f[kt], S);
            }
            unsigned s2p[4];
#pragma unroll
            for (int p = 0; p < 4; ++p) s2p[p] = pk2(S[2 * p], S[2 * p + 1]);
            BUILD_B(Bsig, s2p, 0);
            float tp = tnear + (float)(cbase + c) * FSTEP;
            float sg = fmaxf(S[0], 0.f);
            alphaR = (tp < tmax) ? 1.0f - __expf(-sg * FSTEP) : 0.0f;
        }

        // ---- SH deg-4 enc (computed late to shrink live range) ----
        short8 Benc;
        {
            float inv = rsqrtf(dx * dx + dy * dy + dz * dz);
            float nx = dx * inv, ny = dy * inv, nz = dz * inv;
            float nx2 = nx * nx, ny2 = ny * ny, nz2 = nz * nz;
            float nxy = nx * ny, nyz = ny * nz, nxz = nx * nz;
            float e0 = 0.28209479177387814f;
            float e1 = -0.48860251190291987f * ny;
            float e2 = 0.48860251190291987f * nz;
            float e3 = -0.48860251190291987f * nx;
            float e4 = 1.0925484305920792f * nxy;
            float e5 = -1.0925484305920792f * nyz;
            float e6 = 0.94617469575756f * nz2 - 0.31539156525252f;
            float e7 = -1.0925484305920792f * nxz;
            float e8 = 0.5462742152960396f * (nx2 - ny2);
            float e9 = 0.5900435899266435f * ny * (-3.0f * nx2 + ny2);
            float e10 = 2.890611442640554f * nxy * nz;
            float e11 = 0.4570457994644657f * ny * (1.0f - 5.0f * nz2);
            float e12 = 0.3731763325901154f * nz * (5.0f * nz2 - 3.0f);
            float e13 = 0.4570457994644657f * nx * (1.0f - 5.0f * nz2);
            float e14 = 1.445305721320277f * nz * (nx2 - ny2);
            float e15 = 0.5900435899266435f * nx * (-nx2 + 3.0f * ny2);
            union { unsigned u[4]; short8 v; } bb;
            bb.u[0] = h ? pk2(e8, e9)   : pk2(e0, e1);
            bb.u[1] = h ? pk2(e10, e11) : pk2(e2, e3);
            bb.u[2] = h ? pk2(e12, e13) : pk2(e4, e5);
            bb.u[3] = h ? pk2(e14, e15) : pk2(e6, e7);
            Benc = bb.v;
        }

        // ---- c0: [enc|sig] 32 -> 64 ; weights from global ----
        short8 c0f[4];
#pragma unroll
        for (int nt = 0; nt < 2; ++nt) {
            f32x16 a = z16;
            short8 wv0 = *(const short8*)&wsg[(48 + nt * 2 + 0) * 64 + lane];
            a = MFMA32(wv0, Benc, a);
            short8 wv1 = *(const short8*)&wsg[(48 + nt * 2 + 1) * 64 + lane];
            a = MFMA32(wv1, Bsig, a);
            unsigned pkt[8];
#pragma unroll
            for (int p = 0; p < 8; ++p)
                pkt[p] = pk2(fmaxf(a[2 * p], 0.f), fmaxf(a[2 * p + 1], 0.f));
            BUILD_B(c0f[2 * nt + 0], pkt, 0);
            BUILD_B(c0f[2 * nt + 1], pkt, 4);
        }

        // ---- c1: 64 -> 64 ; weights from global ----
        short8 c1f[4];
#pragma unroll
        for (int nt = 0; nt < 2; ++nt) {
            f32x16 a = z16;
#pragma unroll
            for (int kt = 0; kt < 4; ++kt) {
                short8 wv = *(const short8*)&wsg[(52 + nt * 4 + kt) * 64 + lane];
                a = MFMA32(wv, c0f[kt], a);
            }
            unsigned pkt[8];
#pragma unroll
            for (int p = 0; p < 8; ++p)
                pkt[p] = pk2(fmaxf(a[2 * p], 0.f), fmaxf(a[2 * p + 1], 0.f));
            BUILD_B(c1f[2 * nt + 0], pkt, 0);
            BUILD_B(c1f[2 * nt + 1], pkt, 4);
        }

        // ---- c2: 64 -> 3 ; weights from global ----
        {
            f32x16 F = z16;
#pragma unroll
            for (int kt = 0; kt < 4; ++kt) {
                short8 wv = *(const short8*)&wsg[(60 + kt) * 64 + lane];
                F = MFMA32(wv, c1f[kt], F);
            }
            if (h == 0) {  // rows n=0,1,2 live on half 0, regs 0..2
                float4 cv;
                cv.x = alphaR;
                cv.y = 1.0f / (1.0f + __expf(-F[0]));
                cv.z = 1.0f / (1.0f + __expf(-F[1]));
                cv.w = 1.0f / (1.0f + __expf(-F[2]));
                comp[wr][cbase + c] = cv;
            }
        }
    }

    __syncthreads();

    // ---- composite: waves 0,1 each scan one ray ----
    if (tid < 128) {
        const int cr = tid >> 6;   // local ray 0/1
        const int ln = tid & 63;
        float4 vl = comp[cr][ln];
        float4 vh = comp[cr][ln + 64];
        float a_lo = vl.x, a_hi = vh.x;
        float m_lo = 1.0f - a_lo + 1e-10f;
        float m_hi = 1.0f - a_hi + 1e-10f;

        float p = m_lo;
#pragma unroll
        for (int off = 1; off < 64; off <<= 1) {
            float q = __shfl_up(p, off, 64);
            if (ln >= off) p *= q;
        }
        float ph = m_hi;
#pragma unroll
        for (int off = 1; off < 64; off <<= 1) {
            float q = __shfl_up(ph, off, 64);
            if (ln >= off) ph *= q;
        }
        float total_lo = __shfl(p, 63, 64);
        float e_lo = __shfl_up(p, 1, 64);
        if (ln == 0) e_lo = 1.0f;
        float e_hi = __shfl_up(ph, 1, 64);
        if (ln == 0) e_hi = 1.0f;
        e_hi *= total_lo;

        float w_lo = a_lo * e_lo;
        float w_hi = a_hi * e_hi;

        float sr = w_lo * vl.y + w_hi * vh.y;
        float sg = w_lo * vl.z + w_hi * vh.z;
        float sb = w_lo * vl.w + w_hi * vh.w;
        float sw = w_lo + w_hi;
#pragma unroll
        for (int off = 32; off >= 1; off >>= 1) {
            sr += __shfl_xor(sr, off, 64);
            sg += __shfl_xor(sg, off, 64);
            sb += __shfl_xor(sb, off, 64);
            sw += __shfl_xor(sw, off, 64);
        }
        if (ln == 0) {
            int rg = blockIdx.x * 2 + cr;
            float bg = 1.0f - sw;
            out[rg * 3 + 0] = sr + bg;
            out[rg * 3 + 1] = sg + bg;
            out[rg * 3 + 2] = sb + bg;
        }
    }
}

extern "C" void kernel_launch(void* const* d_in, const int* in_sizes, int n_in,
                              void* d_out, int out_size, void* d_ws, size_t ws_size,
                              hipStream_t stream) {
    const float* rays_o = (const float*)d_in[0];
    const float* rays_d = (const float*)d_in[1];
    const float* G1 = (const float*)d_in[2];
    const float* Fg = (const float*)d_in[3];
    const float* s_w0 = (const float*)d_in[4];
    const float* s_w1 = (const float*)d_in[5];
    const float* s_w2 = (const float*)d_in[6];
    const float* c_w0 = (const float*)d_in[7];
    const float* c_w1 = (const float*)d_in[8];
    const float* c_w2 = (const float*)d_in[9];
    float* out = (float*)d_out;

    const int B = in_sizes[0] / 3;  // 8192 rays
    const int npts = B * 128;

    const size_t FV_OFF = 65536;
    const size_t need = FV_OFF + (size_t)npts * 64;
    if (ws_size < need) return;  // observed ws_size ~805 MB >> 84 MB needed

    uint4* fv = (uint4*)((char*)d_ws + FV_OFF);

    prep_weights_kernel<<<dim3(64), dim3(64), 0, stream>>>(s_w0, s_w1, s_w2, c_w0, c_w1, c_w2,
                                                           (uint4*)d_ws);
    sample_kernel<<<dim3(npts / 256), dim3(256), 0, stream>>>(rays_o, rays_d, G1, Fg, fv);
    mlp_kernel8<<<dim3(B / 2), dim3(512), 0, stream>>>(rays_o, rays_d, (const uint4*)d_ws,
                                                       (const short8*)fv, out);
}